// Round 6
// baseline (672.200 us; speedup 1.0000x reference)
//
#include <hip/hip_runtime.h>
#include <stdint.h>

#define N_NODES 100000
#define N_EDGES 1600000
#define N_GRAPHS 128
#define DIN 100
#define DOUT 200
#define LDH 200   // f16 row stride for 200-dim buffers (400 B)
#define LDX 128   // f16 row stride for 100-dim layer (256 B = 4 lines, aligned)
#define LDT 136   // LDS tile stride (halfs): 272 B = 17x16B aligned, <=2-way banks

#define NB 391       // buckets of 256 nodes (391*256 >= 100000)
#define BCAP 5120    // per-bucket capacity; E/NB=4092, sigma~64 -> +16 sigma margin
#define EPB 2048     // edges per block in bucketize
#define NBLK 782     // ceil(E / EPB)

typedef unsigned short u16;
typedef unsigned int u32;
typedef _Float16 f16;
typedef f16 half8 __attribute__((ext_vector_type(8)));
typedef f16 half4 __attribute__((ext_vector_type(4)));
typedef f16 half2v __attribute__((ext_vector_type(2)));
typedef float floatx4 __attribute__((ext_vector_type(4)));

__device__ __forceinline__ float h2f(u16 h) {
  f16 x; __builtin_memcpy(&x, &h, 2); return (float)x;
}
__device__ __forceinline__ u16 f2h(float f) {
  f16 x = (f16)f; u16 r; __builtin_memcpy(&r, &x, 2); return r;
}
// order-preserving f32 -> u32 encoding (for atomicMax pooling); 0 = "empty"
__device__ __forceinline__ u32 encmax(float f) {
  u32 b; __builtin_memcpy(&b, &f, 4);
  return (b & 0x80000000u) ? ~b : (b | 0x80000000u);
}

// ---------- pack W[K,200] (fp32) into MFMA B-frag order ----------
// frag(ks, ct, lane, j) = f16( W[k][n] ), n = ct*16 + (lane&15), k = ks*32 + (lane>>4)*8 + j
__device__ __forceinline__ void pack_frag(const float* __restrict__ W, int K, int nfrag,
                                          u16* __restrict__ out, int idx) {
  if (idx >= nfrag) return;
  int lane = idx & 63;
  int t = idx >> 6;
  int ct = t % 13, ks = t / 13;
  int n = ct * 16 + (lane & 15);
  int kbase = ks * 32 + (lane >> 4) * 8;
  u16 v[8];
  #pragma unroll
  for (int j = 0; j < 8; ++j) {
    int k = kbase + j;
    float f = (k < K && n < DOUT) ? W[(size_t)k * DOUT + n] : 0.f;
    v[j] = f2h(f);
  }
  uint4 o;
  o.x = (u32)v[0] | ((u32)v[1] << 16);
  o.y = (u32)v[2] | ((u32)v[3] << 16);
  o.z = (u32)v[4] | ((u32)v[5] << 16);
  o.w = (u32)v[6] | ((u32)v[7] << 16);
  *(uint4*)(out + (size_t)idx * 8) = o;
}

// ---------- fused prep: comb | pack1 | pack3 | edge-histogram ----------
#define B_COMB  158
#define B_PK1   171
#define B_PK3   194
#define B_TOT   (194 + NBLK)
__global__ void k_prep(const int* __restrict__ dst, int* __restrict__ histAll,
                       const float* __restrict__ Wc, const float* __restrict__ bc,
                       const float* __restrict__ W2, float* __restrict__ Wc2,
                       float* __restrict__ bc2, const float* __restrict__ W1,
                       const float* __restrict__ W3, u16* __restrict__ Wpk1,
                       u16* __restrict__ Wpk3) {
  int b = blockIdx.x, t = threadIdx.x;
  if (b < B_COMB) {
    int gid = b * 256 + t;
    if (gid >= 201 * DOUT) return;
    int r = gid / DOUT, c = gid % DOUT;
    const float* a = (r < DOUT) ? (Wc + (size_t)r * DOUT) : bc;
    float s = 0.f;
    for (int k = 0; k < DOUT; ++k) s += a[k] * W2[(size_t)k * DOUT + c];
    if (r < DOUT) Wc2[(size_t)r * DOUT + c] = s;
    else bc2[c] = s;
  } else if (b < B_PK1) {
    pack_frag(W1, DIN, 4 * 13 * 64, Wpk1, (b - B_COMB) * 256 + t);
  } else if (b < B_PK3) {
    pack_frag(W3, DOUT, 7 * 13 * 64, Wpk3, (b - B_PK1) * 256 + t);
  } else {
    __shared__ int hist[NB];
    int hb = b - B_PK3;
    int e0 = hb * EPB;
    int e1 = min(e0 + EPB, N_EDGES);
    for (int j = t; j < NB; j += 256) hist[j] = 0;
    __syncthreads();
    for (int i = e0 + t; i < e1; i += 256)
      atomicAdd(&hist[dst[i] >> 8], 1);
    __syncthreads();
    for (int j = t; j < NB; j += 256)
      histAll[(size_t)hb * NB + j] = hist[j];
  }
}

// ---------- per-bucket prefix over blocks + pack2 band ----------
#define SCAN_TOT (NB + 23)
__global__ void k_scan(const int* __restrict__ histAll, int* __restrict__ baseAll,
                       int* __restrict__ gcur, const float* __restrict__ Wc2,
                       u16* __restrict__ Wpk2) {
  int j = blockIdx.x, t = threadIdx.x;
  if (j >= NB) {  // pack2 band (whole blocks -> no divergent barriers)
    pack_frag(Wc2, DOUT, 7 * 13 * 64, Wpk2, (j - NB) * 256 + t);
    return;
  }
  __shared__ int s[256];
  int run = 0;
  for (int c = 0; c < NBLK; c += 256) {
    int idx = c + t;
    int v = (idx < NBLK) ? histAll[(size_t)idx * NB + j] : 0;
    s[t] = v;
    __syncthreads();
    for (int o = 1; o < 256; o <<= 1) {
      int x = (t >= o) ? s[t - o] : 0;
      __syncthreads();
      s[t] += x;
      __syncthreads();
    }
    if (idx < NBLK) baseAll[(size_t)idx * NB + j] = run + s[t] - v;
    run += s[255];
    __syncthreads();
  }
  if (t == 0) gcur[j] = run;
}

// ---------- scatter edges to ebuf at precomputed positions ----------
// R6: ebuf packed to u32 = (src << 8) | (dst & 255)  [src < 2^17, slot < 2^8]
// -> halves scatter write + csr read bytes.
__global__ void k_scatter(const int* __restrict__ src, const int* __restrict__ dst,
                          const int* __restrict__ baseAll, u32* __restrict__ ebuf) {
  __shared__ int cur[NB];
  int b = blockIdx.x, t = threadIdx.x;
  int e0 = b * EPB;
  int e1 = min(e0 + EPB, N_EDGES);
  for (int j = t; j < NB; j += 256) cur[j] = baseAll[(size_t)b * NB + j];
  __syncthreads();
  for (int i = e0 + t; i < e1; i += 256) {
    int d = dst[i];
    int bk = d >> 8;
    int pos = atomicAdd(&cur[bk], 1);
    if (pos < BCAP)
      ebuf[(size_t)bk * BCAP + pos] = ((u32)src[i] << 8) | (u32)(d & 255);
  }
}

// ---------- per-bucket CSR build -> rowptr,dinv,col ; fused xs = dinv*x ; zero partenc ----------
__global__ void k_csr(const u32* __restrict__ ebuf, const int* __restrict__ gcur,
                      int* __restrict__ rowptr, float* __restrict__ dinv,
                      int* __restrict__ colv, const float* __restrict__ x,
                      u16* __restrict__ xs, u32* __restrict__ partenc) {
  __shared__ int s_cnt[256];
  __shared__ int s_cur[256];
  __shared__ int s_scan[256];
  __shared__ int s_g[NB];
  __shared__ int s_red[256];
  __shared__ float s_dinv[256];
  int b = blockIdx.x, t = threadIdx.x;
  int zid = b * 256 + t;
  if (zid < N_GRAPHS * DOUT) partenc[zid] = 0u;
  for (int j = t; j < NB; j += 256) s_g[j] = gcur[j];
  s_cnt[t] = 0;
  __syncthreads();
  // parallel exclusive prefix: base = sum(s_g[0..b-1])
  int pacc = 0;
  for (int i = t; i < b; i += 256) pacc += s_g[i];
  s_red[t] = pacc;
  __syncthreads();
  for (int o = 128; o > 0; o >>= 1) {
    if (t < o) s_red[t] += s_red[t + o];
    __syncthreads();
  }
  int base = s_red[0];
  if (b == NB - 1 && t == 0) rowptr[N_NODES] = base + s_g[b];  // == E
  int cnt = s_g[b];
  int node0 = b << 8;
  const u32* eb = ebuf + (size_t)b * BCAP;
  for (int i = t; i < cnt; i += 256)
    atomicAdd(&s_cnt[eb[i] & 255], 1);
  __syncthreads();
  int v = s_cnt[t];
  s_scan[t] = v;
  __syncthreads();
  for (int o = 1; o < 256; o <<= 1) {
    int x2 = (t >= o) ? s_scan[t - o] : 0;
    __syncthreads();
    s_scan[t] += x2;
    __syncthreads();
  }
  int run = s_scan[t] - v;  // exclusive
  s_cur[t] = base + run;
  float dval = rsqrtf((float)v + 1.0f);
  s_dinv[t] = dval;
  int node = node0 + t;
  if (node < N_NODES) {
    rowptr[node] = base + run;
    dinv[node] = dval;
  }
  __syncthreads();
  for (int i = t; i < cnt; i += 256) {
    u32 e = eb[i];
    int pos = atomicAdd(&s_cur[e & 255], 1);
    colv[pos] = (int)(e >> 8);
  }
  // fused xs band: 256 nodes x 50 half2 each
  for (int idx = t; idx < 256 * 50; idx += 256) {
    int nl = idx / 50, c = idx % 50;
    int nd = node0 + nl;
    if (nd < N_NODES) {
      float d = s_dinv[nl];
      float2 vv = *(const float2*)(x + (size_t)nd * DIN + c * 2);
      half2v o; o[0] = (f16)(d * vv.x); o[1] = (f16)(d * vv.y);
      *(half2v*)(xs + (size_t)nd * LDX + c * 2) = o;
    }
  }
}

// ---------- fused agg100 + GEMM1: buf0 = relu(agg(xs)@W1 + b1) ----------
// R6: wave-private handoff — each wave aggregates ITS 32 output rows into its own
// 32x136 LDS quadrant, then runs its own 32-row GEMM from that quadrant. No HBM
// round-trip for agg output. acc split into 7+6 ct-chunks keeps VGPR <= ~110 so
// occupancy is LDS-capped (34.8KB -> 4 blk/CU = 16 waves/CU, ~= split-kernel occ).
__global__ __launch_bounds__(256) void k_aggemm1(const u16* __restrict__ T,
                                                 const float* __restrict__ dinv,
                                                 const int* __restrict__ rowptr,
                                                 const int* __restrict__ col,
                                                 const u16* __restrict__ Wpk1,
                                                 const float* __restrict__ b1,
                                                 u16* __restrict__ C, int nrows) {
  __shared__ u16 tile[4][32][LDT];
  int wv = threadIdx.x >> 6;
  int lane = threadIdx.x & 63;
  int r0 = blockIdx.x * 128 + wv * 32;
  // rowptr[r0..r0+32] in lanes 0..32 ; dinv bits in lanes 0..31
  int rpl = rowptr[min(r0 + min(lane, 32), N_NODES)];
  int dvb = ((const int*)dinv)[min(r0 + min(lane, 31), N_NODES - 1)];
  int c2 = lane * 2;

  // ---- agg phase: 32 nodes, wave-private ----
  for (int i = 0; i < 32; ++i) {
    int node = r0 + i;
    if (lane >= 50) {  // zero pad cols 100..127 (14 lanes x half2)
      *(half2v*)&tile[wv][i][100 + (lane - 50) * 2] = half2v{0, 0};
      continue;
    }
    if (node >= nrows) {
      *(half2v*)&tile[wv][i][c2] = half2v{0, 0};
      continue;
    }
    int beg = __builtin_amdgcn_readlane(rpl, i);
    int end = __builtin_amdgcn_readlane(rpl, i + 1);
    int dib = __builtin_amdgcn_readlane(dvb, i);
    float di; __builtin_memcpy(&di, &dib, 4);
    half2v sv = *(const half2v*)(T + (size_t)node * LDX + c2);
    float ax = 0.f, ay = 0.f;
    int e = beg;
    for (; e + 16 <= end; e += 16) {
      int s[16];
      half2v tv[16];
      #pragma unroll
      for (int j = 0; j < 16; ++j) s[j] = col[e + j];
      #pragma unroll
      for (int j = 0; j < 16; ++j)
        tv[j] = *(const half2v*)(T + (size_t)s[j] * LDX + c2);
      #pragma unroll
      for (int j = 0; j < 16; ++j) { ax += (float)tv[j][0]; ay += (float)tv[j][1]; }
    }
    if (e + 8 <= end) {
      int s[8];
      half2v tv[8];
      #pragma unroll
      for (int j = 0; j < 8; ++j) s[j] = col[e + j];
      #pragma unroll
      for (int j = 0; j < 8; ++j)
        tv[j] = *(const half2v*)(T + (size_t)s[j] * LDX + c2);
      #pragma unroll
      for (int j = 0; j < 8; ++j) { ax += (float)tv[j][0]; ay += (float)tv[j][1]; }
      e += 8;
    }
    if (e + 4 <= end) {
      int s[4];
      half2v tv[4];
      #pragma unroll
      for (int j = 0; j < 4; ++j) s[j] = col[e + j];
      #pragma unroll
      for (int j = 0; j < 4; ++j)
        tv[j] = *(const half2v*)(T + (size_t)s[j] * LDX + c2);
      #pragma unroll
      for (int j = 0; j < 4; ++j) { ax += (float)tv[j][0]; ay += (float)tv[j][1]; }
      e += 4;
    }
    for (; e < end; ++e) {
      half2v tv = *(const half2v*)(T + (size_t)col[e] * LDX + c2);
      ax += (float)tv[0]; ay += (float)tv[1];
    }
    half2v o;
    o[0] = (f16)(di * (ax + (float)sv[0]));
    o[1] = (f16)(di * (ay + (float)sv[1]));
    *(half2v*)&tile[wv][i][c2] = o;
  }
  __syncthreads();  // LDS visibility (quadrants are wave-private; barrier is belt+braces)

  // ---- gemm phase: 32 rows from own LDS quadrant, 13 ct-tiles in 7+6 chunks ----
  int m = lane & 15, q = lane >> 4;
  const u16* wp = Wpk1 + (size_t)lane * 8;
  #pragma unroll
  for (int half = 0; half < 2; ++half) {
    int ct0 = half * 7;
    int nct = half ? 6 : 7;
    floatx4 acc0[7], acc1[7];
    #pragma unroll
    for (int c = 0; c < 7; ++c) {
      acc0[c] = floatx4{0.f, 0.f, 0.f, 0.f};
      acc1[c] = floatx4{0.f, 0.f, 0.f, 0.f};
    }
    #pragma unroll
    for (int ks = 0; ks < 4; ++ks) {
      half8 a0 = *(const half8*)&tile[wv][m][q * 8 + ks * 32];
      half8 a1 = *(const half8*)&tile[wv][16 + m][q * 8 + ks * 32];
      for (int c = 0; c < nct; ++c) {
        half8 bfr = *(const half8*)(wp + (size_t)(ks * 13 + ct0 + c) * 512);
        acc0[c] = __builtin_amdgcn_mfma_f32_16x16x32_f16(a0, bfr, acc0[c], 0, 0, 0);
        acc1[c] = __builtin_amdgcn_mfma_f32_16x16x32_f16(a1, bfr, acc1[c], 0, 0, 0);
      }
    }
    for (int c = 0; c < nct; ++c) {
      int cc = (ct0 + c) * 16 + m;
      if (cc >= DOUT) continue;
      float bv = b1[cc];
      #pragma unroll
      for (int rg = 0; rg < 4; ++rg) {
        int or0 = r0 + q * 4 + rg;
        if (or0 < nrows)
          C[(size_t)or0 * LDH + cc] = f2h(fmaxf(acc0[c][rg] + bv, 0.f));
        int or1 = r0 + 16 + q * 4 + rg;
        if (or1 < nrows)
          C[(size_t)or1 * LDH + cc] = f2h(fmaxf(acc1[c][rg] + bv, 0.f));
      }
    }
  }
}

// ---------- MFMA GEMM: C = A @ Wpk (+bias)(+relu)(row-scale by dinv), 32 rows/wave ----------
template <int NKS>
__global__ __launch_bounds__(256) void k_gemm_mfma(const u16* __restrict__ A, int lda,
                                                   const u16* __restrict__ Wpk,
                                                   const float* __restrict__ bias,
                                                   const float* __restrict__ rowscale,
                                                   u16* __restrict__ C, int relu, int nrows) {
  int wv = threadIdx.x >> 6;
  int lane = threadIdx.x & 63;
  int r0 = blockIdx.x * 128 + wv * 32;
  int m = lane & 15, q = lane >> 4;
  int row0 = r0 + m, row1 = r0 + 16 + m;
  bool ok0 = (row0 < nrows), ok1 = (row1 < nrows);
  const u16* a0p = A + (size_t)row0 * lda + q * 8;
  const u16* a1p = A + (size_t)row1 * lda + q * 8;

  floatx4 acc0[13], acc1[13];
  #pragma unroll
  for (int ct = 0; ct < 13; ++ct) {
    acc0[ct] = floatx4{0.f, 0.f, 0.f, 0.f};
    acc1[ct] = floatx4{0.f, 0.f, 0.f, 0.f};
  }

  const u16* wp = Wpk + (size_t)lane * 8;
  #pragma unroll
  for (int ks = 0; ks < NKS; ++ks) {
    half8 a0 = ok0 ? *(const half8*)(a0p + ks * 32) : half8{0, 0, 0, 0, 0, 0, 0, 0};
    half8 a1 = ok1 ? *(const half8*)(a1p + ks * 32) : half8{0, 0, 0, 0, 0, 0, 0, 0};
    #pragma unroll
    for (int ct = 0; ct < 13; ++ct) {
      half8 bfr = *(const half8*)(wp + (size_t)(ks * 13 + ct) * 512);
      acc0[ct] = __builtin_amdgcn_mfma_f32_16x16x32_f16(a0, bfr, acc0[ct], 0, 0, 0);
      acc1[ct] = __builtin_amdgcn_mfma_f32_16x16x32_f16(a1, bfr, acc1[ct], 0, 0, 0);
    }
  }

  float sc0[4], sc1[4];
  #pragma unroll
  for (int rg = 0; rg < 4; ++rg) {
    int or0 = r0 + q * 4 + rg;
    int or1 = r0 + 16 + q * 4 + rg;
    sc0[rg] = (rowscale && or0 < nrows) ? rowscale[or0] : 1.f;
    sc1[rg] = (rowscale && or1 < nrows) ? rowscale[or1] : 1.f;
  }

  #pragma unroll
  for (int ct = 0; ct < 13; ++ct) {
    int c = ct * 16 + m;
    if (c >= DOUT) continue;
    float bv = bias ? bias[c] : 0.f;
    #pragma unroll
    for (int rg = 0; rg < 4; ++rg) {
      int or0 = r0 + q * 4 + rg;
      if (or0 < nrows) {
        float v = acc0[ct][rg] + bv;
        if (relu) v = fmaxf(v, 0.f);
        C[(size_t)or0 * LDH + c] = f2h(v * sc0[rg]);
      }
      int or1 = r0 + 16 + q * 4 + rg;
      if (or1 < nrows) {
        float v = acc1[ct][rg] + bv;
        if (relu) v = fmaxf(v, 0.f);
        C[(size_t)or1 * LDH + c] = f2h(v * sc1[rg]);
      }
    }
  }
}

// ---------- aggregation D=200 (R2 best form: 1 node/wave, 16-deep batches) ----------
__global__ void k_agg200h(const u16* __restrict__ T, const float* __restrict__ dinv,
                          const int* __restrict__ rowptr, const int* __restrict__ col,
                          const float* __restrict__ bias, u16* __restrict__ OUT,
                          int relu) {
  int wave = (blockIdx.x * blockDim.x + threadIdx.x) >> 6;
  int lane = threadIdx.x & 63;
  if (wave >= N_NODES || lane >= 50) return;
  int node = wave;
  int c4 = lane * 4;
  int beg = __builtin_amdgcn_readfirstlane(rowptr[node]);
  int end = __builtin_amdgcn_readfirstlane(rowptr[node + 1]);
  half4 sv = *(const half4*)(T + (size_t)node * LDH + c4);
  float di = dinv[node];
  float ax = 0.f, ay = 0.f, az = 0.f, aw = 0.f;
  int e = beg;
  for (; e + 16 <= end; e += 16) {
    int s[16];
    half4 tv[16];
    #pragma unroll
    for (int j = 0; j < 16; ++j) s[j] = col[e + j];
    #pragma unroll
    for (int j = 0; j < 16; ++j)
      tv[j] = *(const half4*)(T + (size_t)s[j] * LDH + c4);
    #pragma unroll
    for (int j = 0; j < 16; ++j) {
      ax += (float)tv[j][0]; ay += (float)tv[j][1];
      az += (float)tv[j][2]; aw += (float)tv[j][3];
    }
  }
  if (e + 8 <= end) {
    int s[8];
    half4 tv[8];
    #pragma unroll
    for (int j = 0; j < 8; ++j) s[j] = col[e + j];
    #pragma unroll
    for (int j = 0; j < 8; ++j)
      tv[j] = *(const half4*)(T + (size_t)s[j] * LDH + c4);
    #pragma unroll
    for (int j = 0; j < 8; ++j) {
      ax += (float)tv[j][0]; ay += (float)tv[j][1];
      az += (float)tv[j][2]; aw += (float)tv[j][3];
    }
    e += 8;
  }
  if (e + 4 <= end) {
    int s[4];
    half4 tv[4];
    #pragma unroll
    for (int j = 0; j < 4; ++j) s[j] = col[e + j];
    #pragma unroll
    for (int j = 0; j < 4; ++j)
      tv[j] = *(const half4*)(T + (size_t)s[j] * LDH + c4);
    #pragma unroll
    for (int j = 0; j < 4; ++j) {
      ax += (float)tv[j][0]; ay += (float)tv[j][1];
      az += (float)tv[j][2]; aw += (float)tv[j][3];
    }
    e += 4;
  }
  for (; e < end; ++e) {
    half4 tv = *(const half4*)(T + (size_t)col[e] * LDH + c4);
    ax += (float)tv[0]; ay += (float)tv[1];
    az += (float)tv[2]; aw += (float)tv[3];
  }
  float rx = di * (ax + (float)sv[0]);
  float ry = di * (ay + (float)sv[1]);
  float rz = di * (az + (float)sv[2]);
  float rw = di * (aw + (float)sv[3]);
  if (bias) {
    rx += bias[c4 + 0]; ry += bias[c4 + 1];
    rz += bias[c4 + 2]; rw += bias[c4 + 3];
  }
  if (relu) {
    rx = fmaxf(rx, 0.f); ry = fmaxf(ry, 0.f);
    rz = fmaxf(rz, 0.f); rw = fmaxf(rw, 0.f);
  }
  half4 o;
  o[0] = (f16)rx; o[1] = (f16)ry; o[2] = (f16)rz; o[3] = (f16)rw;
  __builtin_nontemporal_store(o, (half4*)(OUT + (size_t)node * LDH + c4));
}

// ---------- fused final agg + global max pool ----------
// R6: register pre-max across the wave's 4 nodes (normally one graph) -> one LDS
// atomicMax flush instead of 4 (kills the 8-way-banked atomic storm).
__global__ void k_aggpool(const u16* __restrict__ T, const float* __restrict__ dinv,
                          const int* __restrict__ rowptr, const int* __restrict__ col,
                          const float* __restrict__ bias, const int* __restrict__ batch,
                          u32* __restrict__ partenc) {
  __shared__ u32 s_enc[4][DOUT];
  int t = threadIdx.x;
  for (int i = t; i < 4 * DOUT; i += 256) ((u32*)s_enc)[i] = 0u;
  __syncthreads();
  int wv = t >> 6, lane = t & 63;
  int nb0 = blockIdx.x * 16;        // block's first node (grid exact: 6250*16=100000)
  int n0 = nb0 + wv * 4;            // wave's first node
  int gfirst = batch[nb0];
  int rpl = rowptr[n0 + (lane < 4 ? lane : 4)];  // lanes 0..4 hold rowptr[n0..n0+4]
  if (lane < 50) {
    int c4 = lane * 4;
    float b0 = bias[c4 + 0], b1v = bias[c4 + 1], b2v = bias[c4 + 2], b3v = bias[c4 + 3];
    float mx = 0.f, my = 0.f, mz = 0.f, mw = 0.f;
    int curslot = -1;
    for (int i = 0; i < 4; ++i) {
      int node = n0 + i;
      int beg = __builtin_amdgcn_readlane(rpl, i);
      int end = __builtin_amdgcn_readlane(rpl, i + 1);
      half4 sv = *(const half4*)(T + (size_t)node * LDH + c4);
      float di = dinv[node];
      float ax = 0.f, ay = 0.f, az = 0.f, aw = 0.f;
      int e = beg;
      for (; e + 16 <= end; e += 16) {
        int s[16];
        half4 tv[16];
        #pragma unroll
        for (int j = 0; j < 16; ++j) s[j] = col[e + j];
        #pragma unroll
        for (int j = 0; j < 16; ++j)
          tv[j] = *(const half4*)(T + (size_t)s[j] * LDH + c4);
        #pragma unroll
        for (int j = 0; j < 16; ++j) {
          ax += (float)tv[j][0]; ay += (float)tv[j][1];
          az += (float)tv[j][2]; aw += (float)tv[j][3];
        }
      }
      if (e + 8 <= end) {
        int s[8];
        half4 tv[8];
        #pragma unroll
        for (int j = 0; j < 8; ++j) s[j] = col[e + j];
        #pragma unroll
        for (int j = 0; j < 8; ++j)
          tv[j] = *(const half4*)(T + (size_t)s[j] * LDH + c4);
        #pragma unroll
        for (int j = 0; j < 8; ++j) {
          ax += (float)tv[j][0]; ay += (float)tv[j][1];
          az += (float)tv[j][2]; aw += (float)tv[j][3];
        }
        e += 8;
      }
      if (e + 4 <= end) {
        int s[4];
        half4 tv[4];
        #pragma unroll
        for (int j = 0; j < 4; ++j) s[j] = col[e + j];
        #pragma unroll
        for (int j = 0; j < 4; ++j)
          tv[j] = *(const half4*)(T + (size_t)s[j] * LDH + c4);
        #pragma unroll
        for (int j = 0; j < 4; ++j) {
          ax += (float)tv[j][0]; ay += (float)tv[j][1];
          az += (float)tv[j][2]; aw += (float)tv[j][3];
        }
        e += 4;
      }
      for (; e < end; ++e) {
        half4 tv = *(const half4*)(T + (size_t)col[e] * LDH + c4);
        ax += (float)tv[0]; ay += (float)tv[1];
        az += (float)tv[2]; aw += (float)tv[3];
      }
      float rx = di * (ax + (float)sv[0]) + b0;
      float ry = di * (ay + (float)sv[1]) + b1v;
      float rz = di * (az + (float)sv[2]) + b2v;
      float rw = di * (aw + (float)sv[3]) + b3v;
      int slot = batch[node] - gfirst;
      if (slot != curslot) {
        if (curslot >= 0) {  // flush previous
          if (curslot < 4) {
            atomicMax(&s_enc[curslot][c4 + 0], encmax(mx));
            atomicMax(&s_enc[curslot][c4 + 1], encmax(my));
            atomicMax(&s_enc[curslot][c4 + 2], encmax(mz));
            atomicMax(&s_enc[curslot][c4 + 3], encmax(mw));
          } else {
            u32* p = partenc + (size_t)(gfirst + curslot) * DOUT + c4;
            atomicMax(&p[0], encmax(mx)); atomicMax(&p[1], encmax(my));
            atomicMax(&p[2], encmax(mz)); atomicMax(&p[3], encmax(mw));
          }
        }
        curslot = slot;
        mx = rx; my = ry; mz = rz; mw = rw;
      } else {
        mx = fmaxf(mx, rx); my = fmaxf(my, ry);
        mz = fmaxf(mz, rz); mw = fmaxf(mw, rw);
      }
    }
    if (curslot >= 0) {  // final flush
      if (curslot < 4) {
        atomicMax(&s_enc[curslot][c4 + 0], encmax(mx));
        atomicMax(&s_enc[curslot][c4 + 1], encmax(my));
        atomicMax(&s_enc[curslot][c4 + 2], encmax(mz));
        atomicMax(&s_enc[curslot][c4 + 3], encmax(mw));
      } else {
        u32* p = partenc + (size_t)(gfirst + curslot) * DOUT + c4;
        atomicMax(&p[0], encmax(mx)); atomicMax(&p[1], encmax(my));
        atomicMax(&p[2], encmax(mz)); atomicMax(&p[3], encmax(mw));
      }
    }
  }
  __syncthreads();
  for (int i = t; i < 4 * DOUT; i += 256) {
    u32 v = ((u32*)s_enc)[i];
    if (v) {
      int slot = i / DOUT, d = i % DOUT;
      atomicMax(&partenc[(size_t)(gfirst + slot) * DOUT + d], v);
    }
  }
}

// ---------- classifier + softmax from encoded pooled max ----------
__global__ void k_poolcls(const u32* __restrict__ partenc, const float* __restrict__ Wcls,
                          const float* __restrict__ bcls, float* __restrict__ out) {
  __shared__ float l0s[256], l1s[256];
  int g = blockIdx.x, t = threadIdx.x;
  float c0 = 0.f, c1 = 0.f;
  if (t < DOUT) {
    u32 e = partenc[(size_t)g * DOUT + t];
    float mv;
    if (e == 0u) {
      mv = -3.4e38f;  // empty segment (shouldn't occur)
    } else {
      u32 b = (e & 0x80000000u) ? (e ^ 0x80000000u) : ~e;
      __builtin_memcpy(&mv, &b, 4);
    }
    c0 = mv * Wcls[t * 2 + 0];
    c1 = mv * Wcls[t * 2 + 1];
  }
  l0s[t] = c0; l1s[t] = c1;
  __syncthreads();
  for (int o = 128; o > 0; o >>= 1) {
    if (t < o) { l0s[t] += l0s[t + o]; l1s[t] += l1s[t + o]; }
    __syncthreads();
  }
  if (t == 0) {
    float l0 = l0s[0] + bcls[0], l1 = l1s[0] + bcls[1];
    float m = fmaxf(l0, l1);
    float e0 = expf(l0 - m), e1 = expf(l1 - m);
    float inv = 1.0f / (e0 + e1);
    out[g * 2 + 0] = e0 * inv;
    out[g * 2 + 1] = e1 * inv;
  }
}

static inline size_t align256(size_t x) { return (x + 255) & ~(size_t)255; }

extern "C" void kernel_launch(void* const* d_in, const int* in_sizes, int n_in,
                              void* d_out, int out_size, void* d_ws, size_t ws_size,
                              hipStream_t stream) {
  const float* x     = (const float*)d_in[0];
  const int*   ei    = (const int*)d_in[1];
  const int*   batch = (const int*)d_in[2];
  const float* W1    = (const float*)d_in[3];
  const float* b1    = (const float*)d_in[4];
  const float* Wc    = (const float*)d_in[5];
  const float* bc    = (const float*)d_in[6];
  const float* W2    = (const float*)d_in[7];
  const float* b2    = (const float*)d_in[8];
  const float* W3    = (const float*)d_in[9];
  const float* b3    = (const float*)d_in[10];
  const float* Wcls  = (const float*)d_in[11];
  const float* bcls  = (const float*)d_in[12];
  float* out = (float*)d_out;

  const int N = N_NODES, E = N_EDGES;
  const int* src = ei;
  const int* dst = ei + E;

  char* ws = (char*)d_ws;
  size_t off = 0;
  float* dinv    = (float*)(ws + off); off = align256(off + (size_t)N * 4);
  int*   rowptr  = (int*)  (ws + off); off = align256(off + (size_t)(N + 1) * 4);
  int*   col     = (int*)  (ws + off); off = align256(off + (size_t)E * 4);
  int*   gcur    = (int*)  (ws + off); off = align256(off + (size_t)NB * 4);
  int*   histAll = (int*)  (ws + off); off = align256(off + (size_t)NBLK * NB * 4);
  int*   baseAll = (int*)  (ws + off); off = align256(off + (size_t)NBLK * NB * 4);
  float* Wc2     = (float*)(ws + off); off = align256(off + (size_t)DOUT * DOUT * 4);
  float* bc2     = (float*)(ws + off); off = align256(off + (size_t)DOUT * 4);
  u16*   Wpk1    = (u16*)  (ws + off); off = align256(off + (size_t)4 * 13 * 64 * 8 * 2);
  u16*   Wpk2    = (u16*)  (ws + off); off = align256(off + (size_t)7 * 13 * 64 * 8 * 2);
  u16*   Wpk3    = (u16*)  (ws + off); off = align256(off + (size_t)7 * 13 * 64 * 8 * 2);
  u16*   xs      = (u16*)  (ws + off); off = align256(off + ((size_t)N * LDX + 128) * 2);
  u16*   buf0    = (u16*)  (ws + off); off = align256(off + ((size_t)N * LDH + 128) * 2);
  u16*   buf1    = (u16*)  (ws + off); off = align256(off + ((size_t)N * LDH + 128) * 2);
  u16*   buf2    = (u16*)  (ws + off); off = align256(off + ((size_t)N * LDH + 128) * 2);

  u32*   ebuf    = (u32*)buf0;       // 8.0 MB bucket scratch aliases buf0 (dead before gemm1 out)
  u32*   partenc = (u32*)histAll;    // pooled-max encodings alias histAll (dead after k_scan)

  // 1) prep: Wc@W2 fold, pack W1/W3, per-block edge histograms
  k_prep<<<B_TOT, 256, 0, stream>>>(dst, histAll, Wc, bc, W2, Wc2, bc2,
                                    W1, W3, Wpk1, Wpk3);
  // 2) per-bucket prefix over blocks + pack Wc2 frags
  k_scan<<<SCAN_TOT, 256, 0, stream>>>(histAll, baseAll, gcur, Wc2, Wpk2);
  // 3) scatter edges into bucket order at exact positions (packed u32)
  k_scatter<<<NBLK, 256, 0, stream>>>(src, dst, baseAll, ebuf);
  // 4) per-bucket CSR build -> rowptr, dinv, col ; fused xs = dinv*x ; zero partenc
  k_csr<<<NB, 256, 0, stream>>>(ebuf, gcur, rowptr, dinv, col, x, xs, partenc);

  int gemmb = (N + 127) / 128;
  int aggb  = (N + 3) / 4;       // 1 node/wave, 4 waves/block
  int aggpb = N / 16;            // 16 nodes/block (exact: 6250)

  // layer 1: fused agg(xs)+GEMM W1 (+b1, relu) -> H1 (agg output never hits HBM)
  k_aggemm1<<<gemmb, 256, 0, stream>>>(xs, dinv, rowptr, col, Wpk1, b1, buf0, N);
  // T2s = dinv .* (H1 @ (Wc@W2) + bc@W2)
  k_gemm_mfma<7><<<gemmb, 256, 0, stream>>>(buf0, LDH, Wpk2, bc2, dinv, buf2, 0, N);
  // h2 = relu(di*(sum T2s + T2s_self) + b2)
  k_agg200h<<<aggb, 256, 0, stream>>>(buf2, dinv, rowptr, col, b2, buf0, 1);
  // T3s = dinv .* (h2 @ W3)
  k_gemm_mfma<7><<<gemmb, 256, 0, stream>>>(buf0, LDH, Wpk3, nullptr, dinv, buf1, 0, N);
  // h3 agg fused with global max pool (h3 never written)
  k_aggpool<<<aggpb, 256, 0, stream>>>(buf1, dinv, rowptr, col, b3, batch, partenc);
  // classifier + softmax
  k_poolcls<<<N_GRAPHS, 256, 0, stream>>>(partenc, Wcls, bcls, out);
}

// Round 7
// 642.475 us; speedup vs baseline: 1.0463x; 1.0463x over previous
//
#include <hip/hip_runtime.h>
#include <stdint.h>

#define N_NODES 100000
#define N_EDGES 1600000
#define N_GRAPHS 128
#define DIN 100
#define DOUT 200
#define LDH 200   // f16 row stride for 200-dim buffers (400 B)
#define LDX 128   // f16 row stride for 100-dim layer (256 B = 4 lines, aligned)

#define NB 391       // buckets of 256 nodes (391*256 >= 100000)
#define BCAP 5120    // per-bucket capacity; E/NB=4092, sigma~64 -> +16 sigma margin
#define EPB 2048     // edges per block in bucketize
#define NBLK 782     // ceil(E / EPB)

typedef unsigned short u16;
typedef unsigned int u32;
typedef _Float16 f16;
typedef f16 half8 __attribute__((ext_vector_type(8)));
typedef f16 half4 __attribute__((ext_vector_type(4)));
typedef f16 half2v __attribute__((ext_vector_type(2)));
typedef float floatx4 __attribute__((ext_vector_type(4)));

__device__ __forceinline__ float h2f(u16 h) {
  f16 x; __builtin_memcpy(&x, &h, 2); return (float)x;
}
__device__ __forceinline__ u16 f2h(float f) {
  f16 x = (f16)f; u16 r; __builtin_memcpy(&r, &x, 2); return r;
}
// order-preserving f32 -> u32 encoding (for atomicMax pooling); 0 = "empty"
__device__ __forceinline__ u32 encmax(float f) {
  u32 b; __builtin_memcpy(&b, &f, 4);
  return (b & 0x80000000u) ? ~b : (b | 0x80000000u);
}

// ---------- pack W[K,200] (fp32) into MFMA B-frag order ----------
// frag(ks, ct, lane, j) = f16( W[k][n] ), n = ct*16 + (lane&15), k = ks*32 + (lane>>4)*8 + j
__device__ __forceinline__ void pack_frag(const float* __restrict__ W, int K, int nfrag,
                                          u16* __restrict__ out, int idx) {
  if (idx >= nfrag) return;
  int lane = idx & 63;
  int t = idx >> 6;
  int ct = t % 13, ks = t / 13;
  int n = ct * 16 + (lane & 15);
  int kbase = ks * 32 + (lane >> 4) * 8;
  u16 v[8];
  #pragma unroll
  for (int j = 0; j < 8; ++j) {
    int k = kbase + j;
    float f = (k < K && n < DOUT) ? W[(size_t)k * DOUT + n] : 0.f;
    v[j] = f2h(f);
  }
  uint4 o;
  o.x = (u32)v[0] | ((u32)v[1] << 16);
  o.y = (u32)v[2] | ((u32)v[3] << 16);
  o.z = (u32)v[4] | ((u32)v[5] << 16);
  o.w = (u32)v[6] | ((u32)v[7] << 16);
  *(uint4*)(out + (size_t)idx * 8) = o;
}

// ---------- fused prep: comb | pack1 | pack3 | edge-histogram ----------
#define B_COMB  158
#define B_PK1   171
#define B_PK3   194
#define B_TOT   (194 + NBLK)
__global__ void k_prep(const int* __restrict__ dst, int* __restrict__ histAll,
                       const float* __restrict__ Wc, const float* __restrict__ bc,
                       const float* __restrict__ W2, float* __restrict__ Wc2,
                       float* __restrict__ bc2, const float* __restrict__ W1,
                       const float* __restrict__ W3, u16* __restrict__ Wpk1,
                       u16* __restrict__ Wpk3) {
  int b = blockIdx.x, t = threadIdx.x;
  if (b < B_COMB) {
    int gid = b * 256 + t;
    if (gid >= 201 * DOUT) return;
    int r = gid / DOUT, c = gid % DOUT;
    const float* a = (r < DOUT) ? (Wc + (size_t)r * DOUT) : bc;
    float s = 0.f;
    for (int k = 0; k < DOUT; ++k) s += a[k] * W2[(size_t)k * DOUT + c];
    if (r < DOUT) Wc2[(size_t)r * DOUT + c] = s;
    else bc2[c] = s;
  } else if (b < B_PK1) {
    pack_frag(W1, DIN, 4 * 13 * 64, Wpk1, (b - B_COMB) * 256 + t);
  } else if (b < B_PK3) {
    pack_frag(W3, DOUT, 7 * 13 * 64, Wpk3, (b - B_PK1) * 256 + t);
  } else {
    __shared__ int hist[NB];
    int hb = b - B_PK3;
    int e0 = hb * EPB;
    int e1 = min(e0 + EPB, N_EDGES);
    for (int j = t; j < NB; j += 256) hist[j] = 0;
    __syncthreads();
    for (int i = e0 + t; i < e1; i += 256)
      atomicAdd(&hist[dst[i] >> 8], 1);
    __syncthreads();
    for (int j = t; j < NB; j += 256)
      histAll[(size_t)hb * NB + j] = hist[j];
  }
}

// ---------- per-bucket prefix over blocks + pack2 band ----------
#define SCAN_TOT (NB + 23)
__global__ void k_scan(const int* __restrict__ histAll, int* __restrict__ baseAll,
                       int* __restrict__ gcur, const float* __restrict__ Wc2,
                       u16* __restrict__ Wpk2) {
  int j = blockIdx.x, t = threadIdx.x;
  if (j >= NB) {  // pack2 band (whole blocks -> no divergent barriers)
    pack_frag(Wc2, DOUT, 7 * 13 * 64, Wpk2, (j - NB) * 256 + t);
    return;
  }
  __shared__ int s[256];
  int run = 0;
  for (int c = 0; c < NBLK; c += 256) {
    int idx = c + t;
    int v = (idx < NBLK) ? histAll[(size_t)idx * NB + j] : 0;
    s[t] = v;
    __syncthreads();
    for (int o = 1; o < 256; o <<= 1) {
      int x = (t >= o) ? s[t - o] : 0;
      __syncthreads();
      s[t] += x;
      __syncthreads();
    }
    if (idx < NBLK) baseAll[(size_t)idx * NB + j] = run + s[t] - v;
    run += s[255];
    __syncthreads();
  }
  if (t == 0) gcur[j] = run;
}

// ---------- scatter edges to ebuf at precomputed positions ----------
// ebuf packed u32 = (src << 8) | (dst & 255)  [src < 2^17, slot < 2^8]
__global__ void k_scatter(const int* __restrict__ src, const int* __restrict__ dst,
                          const int* __restrict__ baseAll, u32* __restrict__ ebuf) {
  __shared__ int cur[NB];
  int b = blockIdx.x, t = threadIdx.x;
  int e0 = b * EPB;
  int e1 = min(e0 + EPB, N_EDGES);
  for (int j = t; j < NB; j += 256) cur[j] = baseAll[(size_t)b * NB + j];
  __syncthreads();
  for (int i = e0 + t; i < e1; i += 256) {
    int d = dst[i];
    int bk = d >> 8;
    int pos = atomicAdd(&cur[bk], 1);
    if (pos < BCAP)
      ebuf[(size_t)bk * BCAP + pos] = ((u32)src[i] << 8) | (u32)(d & 255);
  }
}

// ---------- per-bucket CSR build -> rowptr,dinv,col ; fused xs = dinv*x ; zero partenc ----------
__global__ void k_csr(const u32* __restrict__ ebuf, const int* __restrict__ gcur,
                      int* __restrict__ rowptr, float* __restrict__ dinv,
                      int* __restrict__ colv, const float* __restrict__ x,
                      u16* __restrict__ xs, u32* __restrict__ partenc) {
  __shared__ int s_cnt[256];
  __shared__ int s_cur[256];
  __shared__ int s_scan[256];
  __shared__ int s_g[NB];
  __shared__ int s_red[256];
  __shared__ float s_dinv[256];
  int b = blockIdx.x, t = threadIdx.x;
  int zid = b * 256 + t;
  if (zid < N_GRAPHS * DOUT) partenc[zid] = 0u;
  for (int j = t; j < NB; j += 256) s_g[j] = gcur[j];
  s_cnt[t] = 0;
  __syncthreads();
  // parallel exclusive prefix: base = sum(s_g[0..b-1])
  int pacc = 0;
  for (int i = t; i < b; i += 256) pacc += s_g[i];
  s_red[t] = pacc;
  __syncthreads();
  for (int o = 128; o > 0; o >>= 1) {
    if (t < o) s_red[t] += s_red[t + o];
    __syncthreads();
  }
  int base = s_red[0];
  if (b == NB - 1 && t == 0) rowptr[N_NODES] = base + s_g[b];  // == E
  int cnt = s_g[b];
  int node0 = b << 8;
  const u32* eb = ebuf + (size_t)b * BCAP;
  for (int i = t; i < cnt; i += 256)
    atomicAdd(&s_cnt[eb[i] & 255], 1);
  __syncthreads();
  int v = s_cnt[t];
  s_scan[t] = v;
  __syncthreads();
  for (int o = 1; o < 256; o <<= 1) {
    int x2 = (t >= o) ? s_scan[t - o] : 0;
    __syncthreads();
    s_scan[t] += x2;
    __syncthreads();
  }
  int run = s_scan[t] - v;  // exclusive
  s_cur[t] = base + run;
  float dval = rsqrtf((float)v + 1.0f);
  s_dinv[t] = dval;
  int node = node0 + t;
  if (node < N_NODES) {
    rowptr[node] = base + run;
    dinv[node] = dval;
  }
  __syncthreads();
  for (int i = t; i < cnt; i += 256) {
    u32 e = eb[i];
    int pos = atomicAdd(&s_cur[e & 255], 1);
    colv[pos] = (int)(e >> 8);
  }
  // fused xs band: 256 nodes x 50 half2 each
  for (int idx = t; idx < 256 * 50; idx += 256) {
    int nl = idx / 50, c = idx % 50;
    int nd = node0 + nl;
    if (nd < N_NODES) {
      float d = s_dinv[nl];
      float2 vv = *(const float2*)(x + (size_t)nd * DIN + c * 2);
      half2v o; o[0] = (f16)(d * vv.x); o[1] = (f16)(d * vv.y);
      *(half2v*)(xs + (size_t)nd * LDX + c * 2) = o;
    }
  }
}

// ---------- MFMA GEMM: C = A @ Wpk (+bias)(+relu)(row-scale by dinv), 32 rows/wave ----------
// R7: aggemm1 fusion REVERTED (wave-count collapse: 3128 seq waves -> 18% occ,
// 145us vs ~88us split; gather side needs max independent wave count).
template <int NKS>
__global__ __launch_bounds__(256) void k_gemm_mfma(const u16* __restrict__ A, int lda,
                                                   const u16* __restrict__ Wpk,
                                                   const float* __restrict__ bias,
                                                   const float* __restrict__ rowscale,
                                                   u16* __restrict__ C, int relu, int nrows) {
  int wv = threadIdx.x >> 6;
  int lane = threadIdx.x & 63;
  int r0 = blockIdx.x * 128 + wv * 32;
  int m = lane & 15, q = lane >> 4;
  int row0 = r0 + m, row1 = r0 + 16 + m;
  bool ok0 = (row0 < nrows), ok1 = (row1 < nrows);
  const u16* a0p = A + (size_t)row0 * lda + q * 8;
  const u16* a1p = A + (size_t)row1 * lda + q * 8;

  floatx4 acc0[13], acc1[13];
  #pragma unroll
  for (int ct = 0; ct < 13; ++ct) {
    acc0[ct] = floatx4{0.f, 0.f, 0.f, 0.f};
    acc1[ct] = floatx4{0.f, 0.f, 0.f, 0.f};
  }

  const u16* wp = Wpk + (size_t)lane * 8;
  #pragma unroll
  for (int ks = 0; ks < NKS; ++ks) {
    half8 a0 = ok0 ? *(const half8*)(a0p + ks * 32) : half8{0, 0, 0, 0, 0, 0, 0, 0};
    half8 a1 = ok1 ? *(const half8*)(a1p + ks * 32) : half8{0, 0, 0, 0, 0, 0, 0, 0};
    #pragma unroll
    for (int ct = 0; ct < 13; ++ct) {
      half8 bfr = *(const half8*)(wp + (size_t)(ks * 13 + ct) * 512);
      acc0[ct] = __builtin_amdgcn_mfma_f32_16x16x32_f16(a0, bfr, acc0[ct], 0, 0, 0);
      acc1[ct] = __builtin_amdgcn_mfma_f32_16x16x32_f16(a1, bfr, acc1[ct], 0, 0, 0);
    }
  }

  float sc0[4], sc1[4];
  #pragma unroll
  for (int rg = 0; rg < 4; ++rg) {
    int or0 = r0 + q * 4 + rg;
    int or1 = r0 + 16 + q * 4 + rg;
    sc0[rg] = (rowscale && or0 < nrows) ? rowscale[or0] : 1.f;
    sc1[rg] = (rowscale && or1 < nrows) ? rowscale[or1] : 1.f;
  }

  #pragma unroll
  for (int ct = 0; ct < 13; ++ct) {
    int c = ct * 16 + m;
    if (c >= DOUT) continue;
    float bv = bias ? bias[c] : 0.f;
    #pragma unroll
    for (int rg = 0; rg < 4; ++rg) {
      int or0 = r0 + q * 4 + rg;
      if (or0 < nrows) {
        float v = acc0[ct][rg] + bv;
        if (relu) v = fmaxf(v, 0.f);
        C[(size_t)or0 * LDH + c] = f2h(v * sc0[rg]);
      }
      int or1 = r0 + 16 + q * 4 + rg;
      if (or1 < nrows) {
        float v = acc1[ct][rg] + bv;
        if (relu) v = fmaxf(v, 0.f);
        C[(size_t)or1 * LDH + c] = f2h(v * sc1[rg]);
      }
    }
  }
}

// ---------- aggregation D=200 (R2 best form: 1 node/wave, 16-deep batches) ----------
__global__ void k_agg200h(const u16* __restrict__ T, const float* __restrict__ dinv,
                          const int* __restrict__ rowptr, const int* __restrict__ col,
                          const float* __restrict__ bias, u16* __restrict__ OUT,
                          int relu) {
  int wave = (blockIdx.x * blockDim.x + threadIdx.x) >> 6;
  int lane = threadIdx.x & 63;
  if (wave >= N_NODES || lane >= 50) return;
  int node = wave;
  int c4 = lane * 4;
  int beg = __builtin_amdgcn_readfirstlane(rowptr[node]);
  int end = __builtin_amdgcn_readfirstlane(rowptr[node + 1]);
  half4 sv = *(const half4*)(T + (size_t)node * LDH + c4);
  float di = dinv[node];
  float ax = 0.f, ay = 0.f, az = 0.f, aw = 0.f;
  int e = beg;
  for (; e + 16 <= end; e += 16) {
    int s[16];
    half4 tv[16];
    #pragma unroll
    for (int j = 0; j < 16; ++j) s[j] = col[e + j];
    #pragma unroll
    for (int j = 0; j < 16; ++j)
      tv[j] = *(const half4*)(T + (size_t)s[j] * LDH + c4);
    #pragma unroll
    for (int j = 0; j < 16; ++j) {
      ax += (float)tv[j][0]; ay += (float)tv[j][1];
      az += (float)tv[j][2]; aw += (float)tv[j][3];
    }
  }
  if (e + 8 <= end) {
    int s[8];
    half4 tv[8];
    #pragma unroll
    for (int j = 0; j < 8; ++j) s[j] = col[e + j];
    #pragma unroll
    for (int j = 0; j < 8; ++j)
      tv[j] = *(const half4*)(T + (size_t)s[j] * LDH + c4);
    #pragma unroll
    for (int j = 0; j < 8; ++j) {
      ax += (float)tv[j][0]; ay += (float)tv[j][1];
      az += (float)tv[j][2]; aw += (float)tv[j][3];
    }
    e += 8;
  }
  if (e + 4 <= end) {
    int s[4];
    half4 tv[4];
    #pragma unroll
    for (int j = 0; j < 4; ++j) s[j] = col[e + j];
    #pragma unroll
    for (int j = 0; j < 4; ++j)
      tv[j] = *(const half4*)(T + (size_t)s[j] * LDH + c4);
    #pragma unroll
    for (int j = 0; j < 4; ++j) {
      ax += (float)tv[j][0]; ay += (float)tv[j][1];
      az += (float)tv[j][2]; aw += (float)tv[j][3];
    }
    e += 4;
  }
  for (; e < end; ++e) {
    half4 tv = *(const half4*)(T + (size_t)col[e] * LDH + c4);
    ax += (float)tv[0]; ay += (float)tv[1];
    az += (float)tv[2]; aw += (float)tv[3];
  }
  float rx = di * (ax + (float)sv[0]);
  float ry = di * (ay + (float)sv[1]);
  float rz = di * (az + (float)sv[2]);
  float rw = di * (aw + (float)sv[3]);
  if (bias) {
    rx += bias[c4 + 0]; ry += bias[c4 + 1];
    rz += bias[c4 + 2]; rw += bias[c4 + 3];
  }
  if (relu) {
    rx = fmaxf(rx, 0.f); ry = fmaxf(ry, 0.f);
    rz = fmaxf(rz, 0.f); rw = fmaxf(rw, 0.f);
  }
  half4 o;
  o[0] = (f16)rx; o[1] = (f16)ry; o[2] = (f16)rz; o[3] = (f16)rw;
  __builtin_nontemporal_store(o, (half4*)(OUT + (size_t)node * LDH + c4));
}

// ---------- aggregation D=100 (R2 best form, 50 lanes, no dead pad writes) ----------
__global__ void k_agg100h(const u16* __restrict__ T, const float* __restrict__ dinv,
                          const int* __restrict__ rowptr, const int* __restrict__ col,
                          u16* __restrict__ OUT) {
  int wave = (blockIdx.x * blockDim.x + threadIdx.x) >> 6;
  int lane = threadIdx.x & 63;
  if (wave >= N_NODES || lane >= 50) return;
  int node = wave;
  int c2 = lane * 2;
  int beg = __builtin_amdgcn_readfirstlane(rowptr[node]);
  int end = __builtin_amdgcn_readfirstlane(rowptr[node + 1]);
  half2v sv = *(const half2v*)(T + (size_t)node * LDX + c2);
  float di = dinv[node];
  float ax = 0.f, ay = 0.f;
  int e = beg;
  for (; e + 16 <= end; e += 16) {
    int s[16];
    half2v tv[16];
    #pragma unroll
    for (int j = 0; j < 16; ++j) s[j] = col[e + j];
    #pragma unroll
    for (int j = 0; j < 16; ++j)
      tv[j] = *(const half2v*)(T + (size_t)s[j] * LDX + c2);
    #pragma unroll
    for (int j = 0; j < 16; ++j) { ax += (float)tv[j][0]; ay += (float)tv[j][1]; }
  }
  if (e + 8 <= end) {
    int s[8];
    half2v tv[8];
    #pragma unroll
    for (int j = 0; j < 8; ++j) s[j] = col[e + j];
    #pragma unroll
    for (int j = 0; j < 8; ++j)
      tv[j] = *(const half2v*)(T + (size_t)s[j] * LDX + c2);
    #pragma unroll
    for (int j = 0; j < 8; ++j) { ax += (float)tv[j][0]; ay += (float)tv[j][1]; }
    e += 8;
  }
  if (e + 4 <= end) {
    int s[4];
    half2v tv[4];
    #pragma unroll
    for (int j = 0; j < 4; ++j) s[j] = col[e + j];
    #pragma unroll
    for (int j = 0; j < 4; ++j)
      tv[j] = *(const half2v*)(T + (size_t)s[j] * LDX + c2);
    #pragma unroll
    for (int j = 0; j < 4; ++j) { ax += (float)tv[j][0]; ay += (float)tv[j][1]; }
    e += 4;
  }
  for (; e < end; ++e) {
    half2v tv = *(const half2v*)(T + (size_t)col[e] * LDX + c2);
    ax += (float)tv[0]; ay += (float)tv[1];
  }
  half2v o;
  o[0] = (f16)(di * (ax + (float)sv[0]));
  o[1] = (f16)(di * (ay + (float)sv[1]));
  __builtin_nontemporal_store(o, (half2v*)(OUT + (size_t)node * LDX + c2));
}

// ---------- fused final agg + global max pool ----------
// Register pre-max across the wave's 4 nodes (normally one graph) -> one LDS
// atomicMax flush instead of 4.
__global__ void k_aggpool(const u16* __restrict__ T, const float* __restrict__ dinv,
                          const int* __restrict__ rowptr, const int* __restrict__ col,
                          const float* __restrict__ bias, const int* __restrict__ batch,
                          u32* __restrict__ partenc) {
  __shared__ u32 s_enc[4][DOUT];
  int t = threadIdx.x;
  for (int i = t; i < 4 * DOUT; i += 256) ((u32*)s_enc)[i] = 0u;
  __syncthreads();
  int wv = t >> 6, lane = t & 63;
  int nb0 = blockIdx.x * 16;        // block's first node (grid exact: 6250*16=100000)
  int n0 = nb0 + wv * 4;            // wave's first node
  int gfirst = batch[nb0];
  int rpl = rowptr[n0 + (lane < 4 ? lane : 4)];  // lanes 0..4 hold rowptr[n0..n0+4]
  if (lane < 50) {
    int c4 = lane * 4;
    float b0 = bias[c4 + 0], b1v = bias[c4 + 1], b2v = bias[c4 + 2], b3v = bias[c4 + 3];
    float mx = 0.f, my = 0.f, mz = 0.f, mw = 0.f;
    int curslot = -1;
    for (int i = 0; i < 4; ++i) {
      int node = n0 + i;
      int beg = __builtin_amdgcn_readlane(rpl, i);
      int end = __builtin_amdgcn_readlane(rpl, i + 1);
      half4 sv = *(const half4*)(T + (size_t)node * LDH + c4);
      float di = dinv[node];
      float ax = 0.f, ay = 0.f, az = 0.f, aw = 0.f;
      int e = beg;
      for (; e + 16 <= end; e += 16) {
        int s[16];
        half4 tv[16];
        #pragma unroll
        for (int j = 0; j < 16; ++j) s[j] = col[e + j];
        #pragma unroll
        for (int j = 0; j < 16; ++j)
          tv[j] = *(const half4*)(T + (size_t)s[j] * LDH + c4);
        #pragma unroll
        for (int j = 0; j < 16; ++j) {
          ax += (float)tv[j][0]; ay += (float)tv[j][1];
          az += (float)tv[j][2]; aw += (float)tv[j][3];
        }
      }
      if (e + 8 <= end) {
        int s[8];
        half4 tv[8];
        #pragma unroll
        for (int j = 0; j < 8; ++j) s[j] = col[e + j];
        #pragma unroll
        for (int j = 0; j < 8; ++j)
          tv[j] = *(const half4*)(T + (size_t)s[j] * LDH + c4);
        #pragma unroll
        for (int j = 0; j < 8; ++j) {
          ax += (float)tv[j][0]; ay += (float)tv[j][1];
          az += (float)tv[j][2]; aw += (float)tv[j][3];
        }
        e += 8;
      }
      if (e + 4 <= end) {
        int s[4];
        half4 tv[4];
        #pragma unroll
        for (int j = 0; j < 4; ++j) s[j] = col[e + j];
        #pragma unroll
        for (int j = 0; j < 4; ++j)
          tv[j] = *(const half4*)(T + (size_t)s[j] * LDH + c4);
        #pragma unroll
        for (int j = 0; j < 4; ++j) {
          ax += (float)tv[j][0]; ay += (float)tv[j][1];
          az += (float)tv[j][2]; aw += (float)tv[j][3];
        }
        e += 4;
      }
      for (; e < end; ++e) {
        half4 tv = *(const half4*)(T + (size_t)col[e] * LDH + c4);
        ax += (float)tv[0]; ay += (float)tv[1];
        az += (float)tv[2]; aw += (float)tv[3];
      }
      float rx = di * (ax + (float)sv[0]) + b0;
      float ry = di * (ay + (float)sv[1]) + b1v;
      float rz = di * (az + (float)sv[2]) + b2v;
      float rw = di * (aw + (float)sv[3]) + b3v;
      int slot = batch[node] - gfirst;
      if (slot != curslot) {
        if (curslot >= 0) {  // flush previous
          if (curslot < 4) {
            atomicMax(&s_enc[curslot][c4 + 0], encmax(mx));
            atomicMax(&s_enc[curslot][c4 + 1], encmax(my));
            atomicMax(&s_enc[curslot][c4 + 2], encmax(mz));
            atomicMax(&s_enc[curslot][c4 + 3], encmax(mw));
          } else {
            u32* p = partenc + (size_t)(gfirst + curslot) * DOUT + c4;
            atomicMax(&p[0], encmax(mx)); atomicMax(&p[1], encmax(my));
            atomicMax(&p[2], encmax(mz)); atomicMax(&p[3], encmax(mw));
          }
        }
        curslot = slot;
        mx = rx; my = ry; mz = rz; mw = rw;
      } else {
        mx = fmaxf(mx, rx); my = fmaxf(my, ry);
        mz = fmaxf(mz, rz); mw = fmaxf(mw, rw);
      }
    }
    if (curslot >= 0) {  // final flush
      if (curslot < 4) {
        atomicMax(&s_enc[curslot][c4 + 0], encmax(mx));
        atomicMax(&s_enc[curslot][c4 + 1], encmax(my));
        atomicMax(&s_enc[curslot][c4 + 2], encmax(mz));
        atomicMax(&s_enc[curslot][c4 + 3], encmax(mw));
      } else {
        u32* p = partenc + (size_t)(gfirst + curslot) * DOUT + c4;
        atomicMax(&p[0], encmax(mx)); atomicMax(&p[1], encmax(my));
        atomicMax(&p[2], encmax(mz)); atomicMax(&p[3], encmax(mw));
      }
    }
  }
  __syncthreads();
  for (int i = t; i < 4 * DOUT; i += 256) {
    u32 v = ((u32*)s_enc)[i];
    if (v) {
      int slot = i / DOUT, d = i % DOUT;
      atomicMax(&partenc[(size_t)(gfirst + slot) * DOUT + d], v);
    }
  }
}

// ---------- classifier + softmax from encoded pooled max ----------
__global__ void k_poolcls(const u32* __restrict__ partenc, const float* __restrict__ Wcls,
                          const float* __restrict__ bcls, float* __restrict__ out) {
  __shared__ float l0s[256], l1s[256];
  int g = blockIdx.x, t = threadIdx.x;
  float c0 = 0.f, c1 = 0.f;
  if (t < DOUT) {
    u32 e = partenc[(size_t)g * DOUT + t];
    float mv;
    if (e == 0u) {
      mv = -3.4e38f;  // empty segment (shouldn't occur)
    } else {
      u32 b = (e & 0x80000000u) ? (e ^ 0x80000000u) : ~e;
      __builtin_memcpy(&mv, &b, 4);
    }
    c0 = mv * Wcls[t * 2 + 0];
    c1 = mv * Wcls[t * 2 + 1];
  }
  l0s[t] = c0; l1s[t] = c1;
  __syncthreads();
  for (int o = 128; o > 0; o >>= 1) {
    if (t < o) { l0s[t] += l0s[t + o]; l1s[t] += l1s[t + o]; }
    __syncthreads();
  }
  if (t == 0) {
    float l0 = l0s[0] + bcls[0], l1 = l1s[0] + bcls[1];
    float m = fmaxf(l0, l1);
    float e0 = expf(l0 - m), e1 = expf(l1 - m);
    float inv = 1.0f / (e0 + e1);
    out[g * 2 + 0] = e0 * inv;
    out[g * 2 + 1] = e1 * inv;
  }
}

static inline size_t align256(size_t x) { return (x + 255) & ~(size_t)255; }

extern "C" void kernel_launch(void* const* d_in, const int* in_sizes, int n_in,
                              void* d_out, int out_size, void* d_ws, size_t ws_size,
                              hipStream_t stream) {
  const float* x     = (const float*)d_in[0];
  const int*   ei    = (const int*)d_in[1];
  const int*   batch = (const int*)d_in[2];
  const float* W1    = (const float*)d_in[3];
  const float* b1    = (const float*)d_in[4];
  const float* Wc    = (const float*)d_in[5];
  const float* bc    = (const float*)d_in[6];
  const float* W2    = (const float*)d_in[7];
  const float* b2    = (const float*)d_in[8];
  const float* W3    = (const float*)d_in[9];
  const float* b3    = (const float*)d_in[10];
  const float* Wcls  = (const float*)d_in[11];
  const float* bcls  = (const float*)d_in[12];
  float* out = (float*)d_out;

  const int N = N_NODES, E = N_EDGES;
  const int* src = ei;
  const int* dst = ei + E;

  char* ws = (char*)d_ws;
  size_t off = 0;
  float* dinv    = (float*)(ws + off); off = align256(off + (size_t)N * 4);
  int*   rowptr  = (int*)  (ws + off); off = align256(off + (size_t)(N + 1) * 4);
  int*   col     = (int*)  (ws + off); off = align256(off + (size_t)E * 4);
  int*   gcur    = (int*)  (ws + off); off = align256(off + (size_t)NB * 4);
  int*   histAll = (int*)  (ws + off); off = align256(off + (size_t)NBLK * NB * 4);
  int*   baseAll = (int*)  (ws + off); off = align256(off + (size_t)NBLK * NB * 4);
  float* Wc2     = (float*)(ws + off); off = align256(off + (size_t)DOUT * DOUT * 4);
  float* bc2     = (float*)(ws + off); off = align256(off + (size_t)DOUT * 4);
  u16*   Wpk1    = (u16*)  (ws + off); off = align256(off + (size_t)4 * 13 * 64 * 8 * 2);
  u16*   Wpk2    = (u16*)  (ws + off); off = align256(off + (size_t)7 * 13 * 64 * 8 * 2);
  u16*   Wpk3    = (u16*)  (ws + off); off = align256(off + (size_t)7 * 13 * 64 * 8 * 2);
  u16*   xs      = (u16*)  (ws + off); off = align256(off + ((size_t)N * LDX + 128) * 2);
  u16*   bufX    = (u16*)  (ws + off); off = align256(off + ((size_t)N * LDX + 128) * 2);
  u16*   buf0    = (u16*)  (ws + off); off = align256(off + ((size_t)N * LDH + 128) * 2);
  u16*   buf1    = (u16*)  (ws + off); off = align256(off + ((size_t)N * LDH + 128) * 2);
  u16*   buf2    = (u16*)  (ws + off); off = align256(off + ((size_t)N * LDH + 128) * 2);

  u32*   ebuf    = (u32*)buf0;       // 8.0 MB bucket scratch aliases buf0 (dead before gemm1 out)
  u32*   partenc = (u32*)histAll;    // pooled-max encodings alias histAll (dead after k_scan)

  // 1) prep: Wc@W2 fold, pack W1/W3, per-block edge histograms
  k_prep<<<B_TOT, 256, 0, stream>>>(dst, histAll, Wc, bc, W2, Wc2, bc2,
                                    W1, W3, Wpk1, Wpk3);
  // 2) per-bucket prefix over blocks + pack Wc2 frags
  k_scan<<<SCAN_TOT, 256, 0, stream>>>(histAll, baseAll, gcur, Wc2, Wpk2);
  // 3) scatter edges into bucket order at exact positions (packed u32)
  k_scatter<<<NBLK, 256, 0, stream>>>(src, dst, baseAll, ebuf);
  // 4) per-bucket CSR build -> rowptr, dinv, col ; fused xs = dinv*x ; zero partenc
  k_csr<<<NB, 256, 0, stream>>>(ebuf, gcur, rowptr, dinv, col, x, xs, partenc);

  int gemmb = (N + 127) / 128;
  int aggb  = (N + 3) / 4;       // 1 node/wave, 4 waves/block
  int aggpb = N / 16;            // 16 nodes/block (exact: 6250)

  // layer 1: agg(xs) -> GEMM W1 (+b1, relu) -> H1
  k_agg100h<<<aggb, 256, 0, stream>>>(xs, dinv, rowptr, col, bufX);
  k_gemm_mfma<4><<<gemmb, 256, 0, stream>>>(bufX, LDX, Wpk1, b1, nullptr, buf0, 1, N);
  // T2s = dinv .* (H1 @ (Wc@W2) + bc@W2)
  k_gemm_mfma<7><<<gemmb, 256, 0, stream>>>(buf0, LDH, Wpk2, bc2, dinv, buf2, 0, N);
  // h2 = relu(di*(sum T2s + T2s_self) + b2)
  k_agg200h<<<aggb, 256, 0, stream>>>(buf2, dinv, rowptr, col, b2, buf0, 1);
  // T3s = dinv .* (h2 @ W3)
  k_gemm_mfma<7><<<gemmb, 256, 0, stream>>>(buf0, LDH, Wpk3, nullptr, dinv, buf1, 0, N);
  // h3 agg fused with global max pool (h3 never written)
  k_aggpool<<<aggpb, 256, 0, stream>>>(buf1, dinv, rowptr, col, b3, batch, partenc);
  // classifier + softmax
  k_poolcls<<<N_GRAPHS, 256, 0, stream>>>(partenc, Wcls, bcls, out);
}

// Round 8
// 634.413 us; speedup vs baseline: 1.0596x; 1.0127x over previous
//
#include <hip/hip_runtime.h>
#include <stdint.h>

#define N_NODES 100000
#define N_EDGES 1600000
#define N_GRAPHS 128
#define DIN 100
#define DOUT 200
#define LDH 200   // f16 row stride for 200-dim buffers (400 B)
#define LDX 128   // f16 row stride for 100-dim layer (256 B = 4 lines, aligned)

#define NB 391       // buckets of 256 nodes (391*256 >= 100000)
#define BCAP 5120    // per-bucket capacity; E/NB=4092, sigma~64 -> +16 sigma margin
#define EPB 2048     // edges per block in bucketize
#define NBLK 782     // ceil(E / EPB)

typedef unsigned short u16;
typedef unsigned int u32;
typedef _Float16 f16;
typedef f16 half8 __attribute__((ext_vector_type(8)));
typedef f16 half4 __attribute__((ext_vector_type(4)));
typedef f16 half2v __attribute__((ext_vector_type(2)));
typedef float floatx4 __attribute__((ext_vector_type(4)));

__device__ __forceinline__ float h2f(u16 h) {
  f16 x; __builtin_memcpy(&x, &h, 2); return (float)x;
}
__device__ __forceinline__ u16 f2h(float f) {
  f16 x = (f16)f; u16 r; __builtin_memcpy(&r, &x, 2); return r;
}
// order-preserving f32 -> u32 encoding (for atomicMax pooling); 0 = "empty"
__device__ __forceinline__ u32 encmax(float f) {
  u32 b; __builtin_memcpy(&b, &f, 4);
  return (b & 0x80000000u) ? ~b : (b | 0x80000000u);
}

// ---------- pack W[K,200] (fp32) into MFMA B-frag order ----------
// frag(ks, ct, lane, j) = f16( W[k][n] ), n = ct*16 + (lane&15), k = ks*32 + (lane>>4)*8 + j
__device__ __forceinline__ void pack_frag(const float* __restrict__ W, int K, int nfrag,
                                          u16* __restrict__ out, int idx) {
  if (idx >= nfrag) return;
  int lane = idx & 63;
  int t = idx >> 6;
  int ct = t % 13, ks = t / 13;
  int n = ct * 16 + (lane & 15);
  int kbase = ks * 32 + (lane >> 4) * 8;
  u16 v[8];
  #pragma unroll
  for (int j = 0; j < 8; ++j) {
    int k = kbase + j;
    float f = (k < K && n < DOUT) ? W[(size_t)k * DOUT + n] : 0.f;
    v[j] = f2h(f);
  }
  uint4 o;
  o.x = (u32)v[0] | ((u32)v[1] << 16);
  o.y = (u32)v[2] | ((u32)v[3] << 16);
  o.z = (u32)v[4] | ((u32)v[5] << 16);
  o.w = (u32)v[6] | ((u32)v[7] << 16);
  *(uint4*)(out + (size_t)idx * 8) = o;
}

// ---------- fused prep: comb | pack1 | pack3 | zero-gcur ----------
// R8: histogram band DELETED (single-pass atomic scatter replaces hist+scan+scatter).
#define B_COMB  158
#define B_PK1   171
#define B_PK3   194
#define B_TOT   195
__global__ void k_prep(int* __restrict__ gcur,
                       const float* __restrict__ Wc, const float* __restrict__ bc,
                       const float* __restrict__ W2, float* __restrict__ Wc2,
                       float* __restrict__ bc2, const float* __restrict__ W1,
                       const float* __restrict__ W3, u16* __restrict__ Wpk1,
                       u16* __restrict__ Wpk3) {
  int b = blockIdx.x, t = threadIdx.x;
  if (b < B_COMB) {
    int gid = b * 256 + t;
    if (gid >= 201 * DOUT) return;
    int r = gid / DOUT, c = gid % DOUT;
    const float* a = (r < DOUT) ? (Wc + (size_t)r * DOUT) : bc;
    float s = 0.f;
    for (int k = 0; k < DOUT; ++k) s += a[k] * W2[(size_t)k * DOUT + c];
    if (r < DOUT) Wc2[(size_t)r * DOUT + c] = s;
    else bc2[c] = s;
  } else if (b < B_PK1) {
    pack_frag(W1, DIN, 4 * 13 * 64, Wpk1, (b - B_COMB) * 256 + t);
  } else if (b < B_PK3) {
    pack_frag(W3, DOUT, 7 * 13 * 64, Wpk3, (b - B_PK1) * 256 + t);
  } else {
    for (int j = t; j < NB; j += 256) gcur[j] = 0;
  }
}

// ---------- single-pass scatter: LDS count -> global chunk reserve -> write ----------
// R8: replaces {prep-hist, k_scan, k_scatter}. Per-block: count 2048 edges into
// LDS hist, ONE global atomicAdd per nonempty bucket reserves a chunk in gcur,
// then write edges at reserved positions. ~390 global atomics/block (vs 1.6M
// edge-granular). Within-bucket order nondeterministic — same as before (LDS
// cursor atomics were already nondeterministic). ebuf u32 = (src<<8)|(dst&255).
// pack2 band rides along (Wc2 ready: k_prep precedes).
#define SC_TOT (NBLK + 23)
__global__ void k_scatter2(const int* __restrict__ src, const int* __restrict__ dst,
                           int* __restrict__ gcur, u32* __restrict__ ebuf,
                           const float* __restrict__ Wc2, u16* __restrict__ Wpk2) {
  int b = blockIdx.x, t = threadIdx.x;
  if (b >= NBLK) {  // pack2 band
    pack_frag(Wc2, DOUT, 7 * 13 * 64, Wpk2, (b - NBLK) * 256 + t);
    return;
  }
  __shared__ int hist[NB];
  __shared__ int gbase[NB];
  __shared__ int lcur[NB];
  int e0 = b * EPB;
  int e1 = min(e0 + EPB, N_EDGES);
  for (int j = t; j < NB; j += 256) { hist[j] = 0; lcur[j] = 0; }
  __syncthreads();
  int dv[8], sv[8];
  int nv = 0;
  #pragma unroll
  for (int k = 0; k < 8; ++k) {
    int i = e0 + t + k * 256;
    if (i < e1) {
      dv[nv] = dst[i];
      sv[nv] = src[i];
      atomicAdd(&hist[dv[nv] >> 8], 1);
      ++nv;
    }
  }
  __syncthreads();
  for (int j = t; j < NB; j += 256)
    if (hist[j] > 0) gbase[j] = atomicAdd(&gcur[j], hist[j]);
  __syncthreads();
  for (int k = 0; k < nv; ++k) {
    int bk = dv[k] >> 8;
    int pos = gbase[bk] + atomicAdd(&lcur[bk], 1);
    if (pos < BCAP)
      ebuf[(size_t)bk * BCAP + pos] = ((u32)sv[k] << 8) | (u32)(dv[k] & 255);
  }
}

// ---------- per-bucket CSR build -> rowptr,dinv,col ; fused xs = dinv*x ; zero partenc ----------
__global__ void k_csr(const u32* __restrict__ ebuf, const int* __restrict__ gcur,
                      int* __restrict__ rowptr, float* __restrict__ dinv,
                      int* __restrict__ colv, const float* __restrict__ x,
                      u16* __restrict__ xs, u32* __restrict__ partenc) {
  __shared__ int s_cnt[256];
  __shared__ int s_cur[256];
  __shared__ int s_scan[256];
  __shared__ int s_g[NB];
  __shared__ int s_red[256];
  __shared__ float s_dinv[256];
  int b = blockIdx.x, t = threadIdx.x;
  int zid = b * 256 + t;
  if (zid < N_GRAPHS * DOUT) partenc[zid] = 0u;
  for (int j = t; j < NB; j += 256) s_g[j] = gcur[j];
  s_cnt[t] = 0;
  __syncthreads();
  // parallel exclusive prefix: base = sum(s_g[0..b-1])
  int pacc = 0;
  for (int i = t; i < b; i += 256) pacc += s_g[i];
  s_red[t] = pacc;
  __syncthreads();
  for (int o = 128; o > 0; o >>= 1) {
    if (t < o) s_red[t] += s_red[t + o];
    __syncthreads();
  }
  int base = s_red[0];
  if (b == NB - 1 && t == 0) rowptr[N_NODES] = base + s_g[b];  // == E
  int cnt = s_g[b];
  int node0 = b << 8;
  const u32* eb = ebuf + (size_t)b * BCAP;
  for (int i = t; i < cnt; i += 256)
    atomicAdd(&s_cnt[eb[i] & 255], 1);
  __syncthreads();
  int v = s_cnt[t];
  s_scan[t] = v;
  __syncthreads();
  for (int o = 1; o < 256; o <<= 1) {
    int x2 = (t >= o) ? s_scan[t - o] : 0;
    __syncthreads();
    s_scan[t] += x2;
    __syncthreads();
  }
  int run = s_scan[t] - v;  // exclusive
  s_cur[t] = base + run;
  float dval = rsqrtf((float)v + 1.0f);
  s_dinv[t] = dval;
  int node = node0 + t;
  if (node < N_NODES) {
    rowptr[node] = base + run;
    dinv[node] = dval;
  }
  __syncthreads();
  for (int i = t; i < cnt; i += 256) {
    u32 e = eb[i];
    int pos = atomicAdd(&s_cur[e & 255], 1);
    colv[pos] = (int)(e >> 8);
  }
  // fused xs band: 256 nodes x 50 half2 each
  for (int idx = t; idx < 256 * 50; idx += 256) {
    int nl = idx / 50, c = idx % 50;
    int nd = node0 + nl;
    if (nd < N_NODES) {
      float d = s_dinv[nl];
      float2 vv = *(const float2*)(x + (size_t)nd * DIN + c * 2);
      half2v o; o[0] = (f16)(d * vv.x); o[1] = (f16)(d * vv.y);
      *(half2v*)(xs + (size_t)nd * LDX + c * 2) = o;
    }
  }
}

// ---------- MFMA GEMM: C = A @ Wpk (+bias)(+relu)(row-scale by dinv), 32 rows/wave ----------
template <int NKS>
__global__ __launch_bounds__(256) void k_gemm_mfma(const u16* __restrict__ A, int lda,
                                                   const u16* __restrict__ Wpk,
                                                   const float* __restrict__ bias,
                                                   const float* __restrict__ rowscale,
                                                   u16* __restrict__ C, int relu, int nrows) {
  int wv = threadIdx.x >> 6;
  int lane = threadIdx.x & 63;
  int r0 = blockIdx.x * 128 + wv * 32;
  int m = lane & 15, q = lane >> 4;
  int row0 = r0 + m, row1 = r0 + 16 + m;
  bool ok0 = (row0 < nrows), ok1 = (row1 < nrows);
  const u16* a0p = A + (size_t)row0 * lda + q * 8;
  const u16* a1p = A + (size_t)row1 * lda + q * 8;

  floatx4 acc0[13], acc1[13];
  #pragma unroll
  for (int ct = 0; ct < 13; ++ct) {
    acc0[ct] = floatx4{0.f, 0.f, 0.f, 0.f};
    acc1[ct] = floatx4{0.f, 0.f, 0.f, 0.f};
  }

  const u16* wp = Wpk + (size_t)lane * 8;
  #pragma unroll
  for (int ks = 0; ks < NKS; ++ks) {
    half8 a0 = ok0 ? *(const half8*)(a0p + ks * 32) : half8{0, 0, 0, 0, 0, 0, 0, 0};
    half8 a1 = ok1 ? *(const half8*)(a1p + ks * 32) : half8{0, 0, 0, 0, 0, 0, 0, 0};
    #pragma unroll
    for (int ct = 0; ct < 13; ++ct) {
      half8 bfr = *(const half8*)(wp + (size_t)(ks * 13 + ct) * 512);
      acc0[ct] = __builtin_amdgcn_mfma_f32_16x16x32_f16(a0, bfr, acc0[ct], 0, 0, 0);
      acc1[ct] = __builtin_amdgcn_mfma_f32_16x16x32_f16(a1, bfr, acc1[ct], 0, 0, 0);
    }
  }

  float sc0[4], sc1[4];
  #pragma unroll
  for (int rg = 0; rg < 4; ++rg) {
    int or0 = r0 + q * 4 + rg;
    int or1 = r0 + 16 + q * 4 + rg;
    sc0[rg] = (rowscale && or0 < nrows) ? rowscale[or0] : 1.f;
    sc1[rg] = (rowscale && or1 < nrows) ? rowscale[or1] : 1.f;
  }

  #pragma unroll
  for (int ct = 0; ct < 13; ++ct) {
    int c = ct * 16 + m;
    if (c >= DOUT) continue;
    float bv = bias ? bias[c] : 0.f;
    #pragma unroll
    for (int rg = 0; rg < 4; ++rg) {
      int or0 = r0 + q * 4 + rg;
      if (or0 < nrows) {
        float v = acc0[ct][rg] + bv;
        if (relu) v = fmaxf(v, 0.f);
        C[(size_t)or0 * LDH + c] = f2h(v * sc0[rg]);
      }
      int or1 = r0 + 16 + q * 4 + rg;
      if (or1 < nrows) {
        float v = acc1[ct][rg] + bv;
        if (relu) v = fmaxf(v, 0.f);
        C[(size_t)or1 * LDH + c] = f2h(v * sc1[rg]);
      }
    }
  }
}

// ---------- aggregation D=200 (R2 best form: 1 node/wave, 16-deep batches) ----------
__global__ void k_agg200h(const u16* __restrict__ T, const float* __restrict__ dinv,
                          const int* __restrict__ rowptr, const int* __restrict__ col,
                          const float* __restrict__ bias, u16* __restrict__ OUT,
                          int relu) {
  int wave = (blockIdx.x * blockDim.x + threadIdx.x) >> 6;
  int lane = threadIdx.x & 63;
  if (wave >= N_NODES || lane >= 50) return;
  int node = wave;
  int c4 = lane * 4;
  int beg = __builtin_amdgcn_readfirstlane(rowptr[node]);
  int end = __builtin_amdgcn_readfirstlane(rowptr[node + 1]);
  half4 sv = *(const half4*)(T + (size_t)node * LDH + c4);
  float di = dinv[node];
  float ax = 0.f, ay = 0.f, az = 0.f, aw = 0.f;
  int e = beg;
  for (; e + 16 <= end; e += 16) {
    int s[16];
    half4 tv[16];
    #pragma unroll
    for (int j = 0; j < 16; ++j) s[j] = col[e + j];
    #pragma unroll
    for (int j = 0; j < 16; ++j)
      tv[j] = *(const half4*)(T + (size_t)s[j] * LDH + c4);
    #pragma unroll
    for (int j = 0; j < 16; ++j) {
      ax += (float)tv[j][0]; ay += (float)tv[j][1];
      az += (float)tv[j][2]; aw += (float)tv[j][3];
    }
  }
  if (e + 8 <= end) {
    int s[8];
    half4 tv[8];
    #pragma unroll
    for (int j = 0; j < 8; ++j) s[j] = col[e + j];
    #pragma unroll
    for (int j = 0; j < 8; ++j)
      tv[j] = *(const half4*)(T + (size_t)s[j] * LDH + c4);
    #pragma unroll
    for (int j = 0; j < 8; ++j) {
      ax += (float)tv[j][0]; ay += (float)tv[j][1];
      az += (float)tv[j][2]; aw += (float)tv[j][3];
    }
    e += 8;
  }
  if (e + 4 <= end) {
    int s[4];
    half4 tv[4];
    #pragma unroll
    for (int j = 0; j < 4; ++j) s[j] = col[e + j];
    #pragma unroll
    for (int j = 0; j < 4; ++j)
      tv[j] = *(const half4*)(T + (size_t)s[j] * LDH + c4);
    #pragma unroll
    for (int j = 0; j < 4; ++j) {
      ax += (float)tv[j][0]; ay += (float)tv[j][1];
      az += (float)tv[j][2]; aw += (float)tv[j][3];
    }
    e += 4;
  }
  for (; e < end; ++e) {
    half4 tv = *(const half4*)(T + (size_t)col[e] * LDH + c4);
    ax += (float)tv[0]; ay += (float)tv[1];
    az += (float)tv[2]; aw += (float)tv[3];
  }
  float rx = di * (ax + (float)sv[0]);
  float ry = di * (ay + (float)sv[1]);
  float rz = di * (az + (float)sv[2]);
  float rw = di * (aw + (float)sv[3]);
  if (bias) {
    rx += bias[c4 + 0]; ry += bias[c4 + 1];
    rz += bias[c4 + 2]; rw += bias[c4 + 3];
  }
  if (relu) {
    rx = fmaxf(rx, 0.f); ry = fmaxf(ry, 0.f);
    rz = fmaxf(rz, 0.f); rw = fmaxf(rw, 0.f);
  }
  half4 o;
  o[0] = (f16)rx; o[1] = (f16)ry; o[2] = (f16)rz; o[3] = (f16)rw;
  __builtin_nontemporal_store(o, (half4*)(OUT + (size_t)node * LDH + c4));
}

// ---------- aggregation D=100 (R2 best form, 50 lanes, no dead pad writes) ----------
__global__ void k_agg100h(const u16* __restrict__ T, const float* __restrict__ dinv,
                          const int* __restrict__ rowptr, const int* __restrict__ col,
                          u16* __restrict__ OUT) {
  int wave = (blockIdx.x * blockDim.x + threadIdx.x) >> 6;
  int lane = threadIdx.x & 63;
  if (wave >= N_NODES || lane >= 50) return;
  int node = wave;
  int c2 = lane * 2;
  int beg = __builtin_amdgcn_readfirstlane(rowptr[node]);
  int end = __builtin_amdgcn_readfirstlane(rowptr[node + 1]);
  half2v sv = *(const half2v*)(T + (size_t)node * LDX + c2);
  float di = dinv[node];
  float ax = 0.f, ay = 0.f;
  int e = beg;
  for (; e + 16 <= end; e += 16) {
    int s[16];
    half2v tv[16];
    #pragma unroll
    for (int j = 0; j < 16; ++j) s[j] = col[e + j];
    #pragma unroll
    for (int j = 0; j < 16; ++j)
      tv[j] = *(const half2v*)(T + (size_t)s[j] * LDX + c2);
    #pragma unroll
    for (int j = 0; j < 16; ++j) { ax += (float)tv[j][0]; ay += (float)tv[j][1]; }
  }
  if (e + 8 <= end) {
    int s[8];
    half2v tv[8];
    #pragma unroll
    for (int j = 0; j < 8; ++j) s[j] = col[e + j];
    #pragma unroll
    for (int j = 0; j < 8; ++j)
      tv[j] = *(const half2v*)(T + (size_t)s[j] * LDX + c2);
    #pragma unroll
    for (int j = 0; j < 8; ++j) { ax += (float)tv[j][0]; ay += (float)tv[j][1]; }
    e += 8;
  }
  if (e + 4 <= end) {
    int s[4];
    half2v tv[4];
    #pragma unroll
    for (int j = 0; j < 4; ++j) s[j] = col[e + j];
    #pragma unroll
    for (int j = 0; j < 4; ++j)
      tv[j] = *(const half2v*)(T + (size_t)s[j] * LDX + c2);
    #pragma unroll
    for (int j = 0; j < 4; ++j) { ax += (float)tv[j][0]; ay += (float)tv[j][1]; }
    e += 4;
  }
  for (; e < end; ++e) {
    half2v tv = *(const half2v*)(T + (size_t)col[e] * LDX + c2);
    ax += (float)tv[0]; ay += (float)tv[1];
  }
  half2v o;
  o[0] = (f16)(di * (ax + (float)sv[0]));
  o[1] = (f16)(di * (ay + (float)sv[1]));
  __builtin_nontemporal_store(o, (half2v*)(OUT + (size_t)node * LDX + c2));
}

// ---------- fused final agg + global max pool ----------
__global__ void k_aggpool(const u16* __restrict__ T, const float* __restrict__ dinv,
                          const int* __restrict__ rowptr, const int* __restrict__ col,
                          const float* __restrict__ bias, const int* __restrict__ batch,
                          u32* __restrict__ partenc) {
  __shared__ u32 s_enc[4][DOUT];
  int t = threadIdx.x;
  for (int i = t; i < 4 * DOUT; i += 256) ((u32*)s_enc)[i] = 0u;
  __syncthreads();
  int wv = t >> 6, lane = t & 63;
  int nb0 = blockIdx.x * 16;        // block's first node (grid exact: 6250*16=100000)
  int n0 = nb0 + wv * 4;            // wave's first node
  int gfirst = batch[nb0];
  int rpl = rowptr[n0 + (lane < 4 ? lane : 4)];  // lanes 0..4 hold rowptr[n0..n0+4]
  if (lane < 50) {
    int c4 = lane * 4;
    float b0 = bias[c4 + 0], b1v = bias[c4 + 1], b2v = bias[c4 + 2], b3v = bias[c4 + 3];
    float mx = 0.f, my = 0.f, mz = 0.f, mw = 0.f;
    int curslot = -1;
    for (int i = 0; i < 4; ++i) {
      int node = n0 + i;
      int beg = __builtin_amdgcn_readlane(rpl, i);
      int end = __builtin_amdgcn_readlane(rpl, i + 1);
      half4 sv = *(const half4*)(T + (size_t)node * LDH + c4);
      float di = dinv[node];
      float ax = 0.f, ay = 0.f, az = 0.f, aw = 0.f;
      int e = beg;
      for (; e + 16 <= end; e += 16) {
        int s[16];
        half4 tv[16];
        #pragma unroll
        for (int j = 0; j < 16; ++j) s[j] = col[e + j];
        #pragma unroll
        for (int j = 0; j < 16; ++j)
          tv[j] = *(const half4*)(T + (size_t)s[j] * LDH + c4);
        #pragma unroll
        for (int j = 0; j < 16; ++j) {
          ax += (float)tv[j][0]; ay += (float)tv[j][1];
          az += (float)tv[j][2]; aw += (float)tv[j][3];
        }
      }
      if (e + 8 <= end) {
        int s[8];
        half4 tv[8];
        #pragma unroll
        for (int j = 0; j < 8; ++j) s[j] = col[e + j];
        #pragma unroll
        for (int j = 0; j < 8; ++j)
          tv[j] = *(const half4*)(T + (size_t)s[j] * LDH + c4);
        #pragma unroll
        for (int j = 0; j < 8; ++j) {
          ax += (float)tv[j][0]; ay += (float)tv[j][1];
          az += (float)tv[j][2]; aw += (float)tv[j][3];
        }
        e += 8;
      }
      if (e + 4 <= end) {
        int s[4];
        half4 tv[4];
        #pragma unroll
        for (int j = 0; j < 4; ++j) s[j] = col[e + j];
        #pragma unroll
        for (int j = 0; j < 4; ++j)
          tv[j] = *(const half4*)(T + (size_t)s[j] * LDH + c4);
        #pragma unroll
        for (int j = 0; j < 4; ++j) {
          ax += (float)tv[j][0]; ay += (float)tv[j][1];
          az += (float)tv[j][2]; aw += (float)tv[j][3];
        }
        e += 4;
      }
      for (; e < end; ++e) {
        half4 tv = *(const half4*)(T + (size_t)col[e] * LDH + c4);
        ax += (float)tv[0]; ay += (float)tv[1];
        az += (float)tv[2]; aw += (float)tv[3];
      }
      float rx = di * (ax + (float)sv[0]) + b0;
      float ry = di * (ay + (float)sv[1]) + b1v;
      float rz = di * (az + (float)sv[2]) + b2v;
      float rw = di * (aw + (float)sv[3]) + b3v;
      int slot = batch[node] - gfirst;
      if (slot != curslot) {
        if (curslot >= 0) {  // flush previous
          if (curslot < 4) {
            atomicMax(&s_enc[curslot][c4 + 0], encmax(mx));
            atomicMax(&s_enc[curslot][c4 + 1], encmax(my));
            atomicMax(&s_enc[curslot][c4 + 2], encmax(mz));
            atomicMax(&s_enc[curslot][c4 + 3], encmax(mw));
          } else {
            u32* p = partenc + (size_t)(gfirst + curslot) * DOUT + c4;
            atomicMax(&p[0], encmax(mx)); atomicMax(&p[1], encmax(my));
            atomicMax(&p[2], encmax(mz)); atomicMax(&p[3], encmax(mw));
          }
        }
        curslot = slot;
        mx = rx; my = ry; mz = rz; mw = rw;
      } else {
        mx = fmaxf(mx, rx); my = fmaxf(my, ry);
        mz = fmaxf(mz, rz); mw = fmaxf(mw, rw);
      }
    }
    if (curslot >= 0) {  // final flush
      if (curslot < 4) {
        atomicMax(&s_enc[curslot][c4 + 0], encmax(mx));
        atomicMax(&s_enc[curslot][c4 + 1], encmax(my));
        atomicMax(&s_enc[curslot][c4 + 2], encmax(mz));
        atomicMax(&s_enc[curslot][c4 + 3], encmax(mw));
      } else {
        u32* p = partenc + (size_t)(gfirst + curslot) * DOUT + c4;
        atomicMax(&p[0], encmax(mx)); atomicMax(&p[1], encmax(my));
        atomicMax(&p[2], encmax(mz)); atomicMax(&p[3], encmax(mw));
      }
    }
  }
  __syncthreads();
  for (int i = t; i < 4 * DOUT; i += 256) {
    u32 v = ((u32*)s_enc)[i];
    if (v) {
      int slot = i / DOUT, d = i % DOUT;
      atomicMax(&partenc[(size_t)(gfirst + slot) * DOUT + d], v);
    }
  }
}

// ---------- classifier + softmax from encoded pooled max ----------
__global__ void k_poolcls(const u32* __restrict__ partenc, const float* __restrict__ Wcls,
                          const float* __restrict__ bcls, float* __restrict__ out) {
  __shared__ float l0s[256], l1s[256];
  int g = blockIdx.x, t = threadIdx.x;
  float c0 = 0.f, c1 = 0.f;
  if (t < DOUT) {
    u32 e = partenc[(size_t)g * DOUT + t];
    float mv;
    if (e == 0u) {
      mv = -3.4e38f;  // empty segment (shouldn't occur)
    } else {
      u32 b = (e & 0x80000000u) ? (e ^ 0x80000000u) : ~e;
      __builtin_memcpy(&mv, &b, 4);
    }
    c0 = mv * Wcls[t * 2 + 0];
    c1 = mv * Wcls[t * 2 + 1];
  }
  l0s[t] = c0; l1s[t] = c1;
  __syncthreads();
  for (int o = 128; o > 0; o >>= 1) {
    if (t < o) { l0s[t] += l0s[t + o]; l1s[t] += l1s[t + o]; }
    __syncthreads();
  }
  if (t == 0) {
    float l0 = l0s[0] + bcls[0], l1 = l1s[0] + bcls[1];
    float m = fmaxf(l0, l1);
    float e0 = expf(l0 - m), e1 = expf(l1 - m);
    float inv = 1.0f / (e0 + e1);
    out[g * 2 + 0] = e0 * inv;
    out[g * 2 + 1] = e1 * inv;
  }
}

static inline size_t align256(size_t x) { return (x + 255) & ~(size_t)255; }

extern "C" void kernel_launch(void* const* d_in, const int* in_sizes, int n_in,
                              void* d_out, int out_size, void* d_ws, size_t ws_size,
                              hipStream_t stream) {
  const float* x     = (const float*)d_in[0];
  const int*   ei    = (const int*)d_in[1];
  const int*   batch = (const int*)d_in[2];
  const float* W1    = (const float*)d_in[3];
  const float* b1    = (const float*)d_in[4];
  const float* Wc    = (const float*)d_in[5];
  const float* bc    = (const float*)d_in[6];
  const float* W2    = (const float*)d_in[7];
  const float* b2    = (const float*)d_in[8];
  const float* W3    = (const float*)d_in[9];
  const float* b3    = (const float*)d_in[10];
  const float* Wcls  = (const float*)d_in[11];
  const float* bcls  = (const float*)d_in[12];
  float* out = (float*)d_out;

  const int N = N_NODES, E = N_EDGES;
  const int* src = ei;
  const int* dst = ei + E;

  char* ws = (char*)d_ws;
  size_t off = 0;
  float* dinv    = (float*)(ws + off); off = align256(off + (size_t)N * 4);
  int*   rowptr  = (int*)  (ws + off); off = align256(off + (size_t)(N + 1) * 4);
  int*   col     = (int*)  (ws + off); off = align256(off + (size_t)E * 4);
  int*   gcur    = (int*)  (ws + off); off = align256(off + (size_t)NB * 4);
  u32*   partenc = (u32*)  (ws + off); off = align256(off + (size_t)N_GRAPHS * DOUT * 4);
  float* Wc2     = (float*)(ws + off); off = align256(off + (size_t)DOUT * DOUT * 4);
  float* bc2     = (float*)(ws + off); off = align256(off + (size_t)DOUT * 4);
  u16*   Wpk1    = (u16*)  (ws + off); off = align256(off + (size_t)4 * 13 * 64 * 8 * 2);
  u16*   Wpk2    = (u16*)  (ws + off); off = align256(off + (size_t)7 * 13 * 64 * 8 * 2);
  u16*   Wpk3    = (u16*)  (ws + off); off = align256(off + (size_t)7 * 13 * 64 * 8 * 2);
  u16*   xs      = (u16*)  (ws + off); off = align256(off + ((size_t)N * LDX + 128) * 2);
  u16*   bufX    = (u16*)  (ws + off); off = align256(off + ((size_t)N * LDX + 128) * 2);
  u16*   buf0    = (u16*)  (ws + off); off = align256(off + ((size_t)N * LDH + 128) * 2);
  u16*   buf1    = (u16*)  (ws + off); off = align256(off + ((size_t)N * LDH + 128) * 2);
  u16*   buf2    = (u16*)  (ws + off); off = align256(off + ((size_t)N * LDH + 128) * 2);

  u32*   ebuf    = (u32*)buf0;   // 8.0 MB bucket scratch aliases buf0 (dead before gemm1 out)

  // 1) prep: Wc@W2 fold, pack W1/W3, zero gcur
  k_prep<<<B_TOT, 256, 0, stream>>>(gcur, Wc, bc, W2, Wc2, bc2, W1, W3, Wpk1, Wpk3);
  // 2) single-pass atomic scatter (+ pack Wc2 frags band)
  k_scatter2<<<SC_TOT, 256, 0, stream>>>(src, dst, gcur, ebuf, Wc2, Wpk2);
  // 3) per-bucket CSR build -> rowptr, dinv, col ; fused xs = dinv*x ; zero partenc
  k_csr<<<NB, 256, 0, stream>>>(ebuf, gcur, rowptr, dinv, col, x, xs, partenc);

  int gemmb = (N + 127) / 128;
  int aggb  = (N + 3) / 4;       // 1 node/wave, 4 waves/block
  int aggpb = N / 16;            // 16 nodes/block (exact: 6250)

  // layer 1: agg(xs) -> GEMM W1 (+b1, relu) -> H1
  k_agg100h<<<aggb, 256, 0, stream>>>(xs, dinv, rowptr, col, bufX);
  k_gemm_mfma<4><<<gemmb, 256, 0, stream>>>(bufX, LDX, Wpk1, b1, nullptr, buf0, 1, N);
  // T2s = dinv .* (H1 @ (Wc@W2) + bc@W2)
  k_gemm_mfma<7><<<gemmb, 256, 0, stream>>>(buf0, LDH, Wpk2, bc2, dinv, buf2, 0, N);
  // h2 = relu(di*(sum T2s + T2s_self) + b2)
  k_agg200h<<<aggb, 256, 0, stream>>>(buf2, dinv, rowptr, col, b2, buf0, 1);
  // T3s = dinv .* (h2 @ W3)
  k_gemm_mfma<7><<<gemmb, 256, 0, stream>>>(buf0, LDH, Wpk3, nullptr, dinv, buf1, 0, N);
  // h3 agg fused with global max pool (h3 never written)
  k_aggpool<<<aggpb, 256, 0, stream>>>(buf1, dinv, rowptr, col, b3, batch, partenc);
  // classifier + softmax
  k_poolcls<<<N_GRAPHS, 256, 0, stream>>>(partenc, Wcls, bcls, out);
}